// Round 8
// baseline (328.805 us; speedup 1.0000x reference)
//
#include <hip/hip_runtime.h>
#include <stdint.h>

#define DIM 128
#define NPROJ 256
#define TPB 128                    // tokens per block (8 waves x 16)
#define TAU 0.016f                 // refine threshold on |k_proj_f16| (~7 sigma of f16 dot err)
#define QCAP 512
#define DEQ 0.004895758348888673f  // sqrt(pi/2)/256

typedef _Float16 f16x8 __attribute__((ext_vector_type(8)));
typedef float f32x4 __attribute__((ext_vector_type(4)));

// ---- prep: S fp32 -> f16 B-fragments, pre-swizzled into MFMA lane order ----
// frag fid = c*8 + ks*2 + f; lane l holds B[n=p][k=d]: p = c*32 + f*16 + (l&15),
// d = ks*32 + (l>>4)*8 + j
__global__ __launch_bounds__(256) void qjl_prep(const float* __restrict__ Sg,
                                                _Float16* __restrict__ ws) {
    int t = blockIdx.x * 256 + threadIdx.x;   // 0..4095
    int lane = t & 63, fid = t >> 6;          // 64 frags
    int f = fid & 1, ks = (fid >> 1) & 3, c = fid >> 3;
    int p = c * 32 + f * 16 + (lane & 15);
    int d0 = ks * 32 + (lane >> 4) * 8;
    const float4* s4 = (const float4*)(Sg + p * DIM + d0);
    float4 a = s4[0], b = s4[1];
    f16x8 h = {(_Float16)a.x, (_Float16)a.y, (_Float16)a.z, (_Float16)a.w,
               (_Float16)b.x, (_Float16)b.y, (_Float16)b.z, (_Float16)b.w};
    *(f16x8*)(ws + (size_t)fid * 512 + lane * 8) = h;
}

// async stage: 2 chunks (16 KB) starting at chunk C0 from ws -> LDS buffer buf.
// 512 threads x 16B = 8 KB per call, 2 calls. src/dst both linear -> coalesced.
#define STAGE(buf, C0)                                                               \
    { const char* gsrc = (const char*)(ws + (size_t)(C0) * 4096) + tid * 16;         \
      char* ldst = (char*)(buf) + tid * 16;                                          \
      _Pragma("unroll")                                                              \
      for (int r = 0; r < 2; ++r)                                                    \
          __builtin_amdgcn_global_load_lds(                                          \
              (const __attribute__((address_space(1))) void*)(gsrc + r * 8192),      \
              (__attribute__((address_space(3))) void*)(ldst + r * 8192),            \
              16, 0, 0); }

// load the 4 B-frags of (local chunk CL in buffer buf, tile T) into named regs
// contiguous lane*16B pattern -> conflict-free ds_read_b128
#define LOADT(dst, buf, CL, T)                                                       \
    { _Pragma("unroll")                                                              \
      for (int ks = 0; ks < 4; ++ks)                                                 \
          dst[ks] = *(const f16x8*)((buf) + ((CL) * 8 + ks * 2 + (T)) * 512 + lane * 8); }

// A fragments (16 K or Q rows per wave) fp32 -> f16 into dst[4]
#define LOADA(dst, src)                                                              \
    { const float* rp = (src) + (tok0 + wv * 16 + m) * DIM;                          \
      _Pragma("unroll")                                                              \
      for (int ks = 0; ks < 4; ++ks) {                                               \
          int d0 = ks * 32 + quad * 8;                                               \
          float4 x = *(const float4*)(rp + d0);                                      \
          float4 y = *(const float4*)(rp + d0 + 4);                                  \
          dst[ks] = (f16x8){(_Float16)x.x, (_Float16)x.y, (_Float16)x.z, (_Float16)x.w, \
                            (_Float16)y.x, (_Float16)y.y, (_Float16)y.z, (_Float16)y.w}; } }

// Fused step: k_proj and q_proj on the same B tile; est += sign(k)*q directly.
// Near-zero k_proj -> candidate queue; store the f16-path q_proj (q0[r]) so the
// refine pass needs only the exact k-dot (patch subtracts exactly what was added).
#define F_STEP(C, T, buf)                                                            \
    { f32x4 k0 = {0,0,0,0}, q0 = {0,0,0,0};                                          \
      _Pragma("unroll")                                                              \
      for (int ks = 0; ks < 4; ++ks) {                                               \
          k0 = __builtin_amdgcn_mfma_f32_16x16x32_f16(ak[ks], buf[ks], k0, 0,0,0);   \
          q0 = __builtin_amdgcn_mfma_f32_16x16x32_f16(aq[ks], buf[ks], q0, 0,0,0);   \
      }                                                                              \
      _Pragma("unroll")                                                              \
      for (int r = 0; r < 4; ++r) {                                                  \
          uint32_t s0 = __float_as_uint(k0[r]) & 0x80000000u;                        \
          est[r] += __uint_as_float(__float_as_uint(q0[r]) ^ s0);                    \
          if (__builtin_expect(fabsf(k0[r]) < TAU, 0)) {                             \
              int idx = atomicAdd(&qn, 1);                                           \
              if (idx < QCAP) {                                                      \
                  qmeta[idx] = (uint32_t)(wv * 16 + quad * 4 + r)                    \
                      | ((uint32_t)((C) * 32 + (T) * 16 + m) << 8)                   \
                      | ((s0 ? 0u : 1u) << 16);                                      \
                  qval[idx] = q0[r];                                                 \
              }                                                                      \
          } } }

// process the 2 chunks held in buffer buf (global chunks C0, C0+1)
#define PHASE(buf, C0)                                                               \
    LOADT(tA, buf, 0, 0);                                                            \
    LOADT(tB, buf, 0, 1);                                                            \
    F_STEP(C0,     0, tA); LOADT(tA, buf, 1, 0);                                     \
    F_STEP(C0,     1, tB); LOADT(tB, buf, 1, 1);                                     \
    F_STEP(C0 + 1, 0, tA);                                                           \
    F_STEP(C0 + 1, 1, tB);

// 8-wave 512-thread blocks + streamed 37KB LDS. Cross-round evidence says the
// machine holds ~2 workgroups (~8 waves)/CU for this kernel regardless of LDS
// and VGPR headroom (rounds 5/6/7 all ~22% occ): bigger blocks under the same
// WG cap = 16 waves/CU, and half as many fixed-cost block prologues/tails.
// 512-thr shape + (512,2) proven no-spill at 92 VGPR (round 6); streaming
// proven in round 7. Register-resident B (rounds 1/3/4) always spilled.
__global__ __launch_bounds__(512, 2) void qjl_main(
    const float* __restrict__ qg, const float* __restrict__ kg,
    const float* __restrict__ Sg, const _Float16* __restrict__ ws,
    float* __restrict__ out)
{
    __shared__ _Float16 bs[2][8192];   // 2 x 16 KB: 2 chunks each
    __shared__ float    est_s[TPB];
    __shared__ uint32_t qmeta[QCAP];
    __shared__ float    qval[QCAP];
    __shared__ int      qn;

    const int tid = threadIdx.x, lane = tid & 63, wv = tid >> 6;   // wv 0..7
    const int m = lane & 15, quad = lane >> 4;
    const long tok0 = (long)blockIdx.x * TPB;
    if (tid == 0) qn = 0;

    f16x8 ak[4], aq[4];        // A fragments: 16 K rows + 16 Q rows
    f16x8 tA[4], tB[4];        // B tile double buffer (fed from LDS)
    float est[4] = {0.f, 0.f, 0.f, 0.f};

    // prologue: both LDS buffers + A rows in flight together
    STAGE(bs[0], 0);           // chunks 0,1
    STAGE(bs[1], 2);           // chunks 2,3
    LOADA(ak, kg);
    LOADA(aq, qg);
    __syncthreads();           // drains vmcnt: stages + A loads complete

    PHASE(bs[0], 0);
    __syncthreads();           // all waves done reading bs[0]
    STAGE(bs[0], 4);           // chunks 4,5 in flight under next phase
    PHASE(bs[1], 2);
    __syncthreads();           // drains stage; all done reading bs[1]
    STAGE(bs[1], 6);           // chunks 6,7 in flight
    PHASE(bs[0], 4);
    __syncthreads();           // drains stage
    PHASE(bs[1], 6);

    // ---- reduce est over the 16 proj-lanes ----
    #pragma unroll
    for (int r = 0; r < 4; ++r) {
        float e = est[r];
        e += __shfl_xor(e, 1);
        e += __shfl_xor(e, 2);
        e += __shfl_xor(e, 4);
        e += __shfl_xor(e, 8);
        if (m == 0) est_s[wv * 16 + quad * 4 + r] = DEQ * e;
    }
    __syncthreads();

    // ---- refine: exact fp64 k-dot; patch with the stored q_proj on sign flip ----
    int nc = qn < QCAP ? qn : QCAP;
    for (int i = tid; i < nc; i += 512) {
        uint32_t mm = qmeta[i];
        int tl = mm & 255;
        int p  = (mm >> 8) & 255;
        int sf = (mm >> 16) & 1;
        const float4* kr = (const float4*)(kg + (tok0 + tl) * DIM);
        const float4* sr = (const float4*)(Sg + (long)p * DIM);
        double dk = 0.0;
        #pragma unroll 8
        for (int j = 0; j < 32; ++j) {
            float4 kv4 = kr[j], sv4 = sr[j];
            dk += (double)kv4.x * (double)sv4.x + (double)kv4.y * (double)sv4.y
                + (double)kv4.z * (double)sv4.z + (double)kv4.w * (double)sv4.w;
        }
        int st = (dk > 0.0) ? 1 : 0;
        if (st != sf) {
            float sg = sf ? 1.f : -1.f;
            atomicAdd(&est_s[tl], -2.f * DEQ * qval[i] * sg);
        }
    }
    __syncthreads();

    if (tid < TPB) out[tok0 + tid] = est_s[tid];
}

extern "C" void kernel_launch(void* const* d_in, const int* in_sizes, int n_in,
                              void* d_out, int out_size, void* d_ws, size_t ws_size,
                              hipStream_t stream) {
    const float* q = (const float*)d_in[0];
    const float* k = (const float*)d_in[1];
    const float* S = (const float*)d_in[2];
    float* out = (float*)d_out;
    _Float16* ws = (_Float16*)d_ws;
    hipLaunchKernelGGL(qjl_prep, dim3(16), dim3(256), 0, stream, S, ws);
    int nblocks = out_size / TPB;   // 262144 / 128 = 2048
    hipLaunchKernelGGL(qjl_main, dim3(nblocks), dim3(512), 0, stream, q, k, S, ws, out);
}

// Round 9
// 297.743 us; speedup vs baseline: 1.1043x; 1.1043x over previous
//
#include <hip/hip_runtime.h>
#include <stdint.h>

#define DIM 128
#define NPROJ 256
#define TAU 0.016f                 // refine threshold on |k_proj_f16| (~7 sigma of f16 dot err)
#define QCAPW 64                   // per-wave candidate queue (expect ~5/tile)
#define DEQ 0.004895758348888673f  // sqrt(pi/2)/256
#define NBLK 512                   // persistent blocks: 2 per CU (observed residency cap)

typedef _Float16 f16x8 __attribute__((ext_vector_type(8)));
typedef float f32x4 __attribute__((ext_vector_type(4)));

// ---- prep: S fp32 -> f16 B-fragments, pre-swizzled into MFMA lane order ----
// frag fid = c*8 + ks*2 + f; lane l holds B[n=p][k=d]: p = c*32 + f*16 + (l&15),
// d = ks*32 + (l>>4)*8 + j
__global__ __launch_bounds__(256) void qjl_prep(const float* __restrict__ Sg,
                                                _Float16* __restrict__ ws) {
    int t = blockIdx.x * 256 + threadIdx.x;   // 0..4095
    int lane = t & 63, fid = t >> 6;          // 64 frags
    int f = fid & 1, ks = (fid >> 1) & 3, c = fid >> 3;
    int p = c * 32 + f * 16 + (lane & 15);
    int d0 = ks * 32 + (lane >> 4) * 8;
    const float4* s4 = (const float4*)(Sg + p * DIM + d0);
    float4 a = s4[0], b = s4[1];
    f16x8 h = {(_Float16)a.x, (_Float16)a.y, (_Float16)a.z, (_Float16)a.w,
               (_Float16)b.x, (_Float16)b.y, (_Float16)b.z, (_Float16)b.w};
    *(f16x8*)(ws + (size_t)fid * 512 + lane * 8) = h;
}

// load the 4 B-frags of (chunk C, tile T) from LDS into named regs
// contiguous lane*16B pattern -> conflict-free ds_read_b128
#define LOADT(dst, C, T)                                                             \
    { _Pragma("unroll")                                                              \
      for (int ks = 0; ks < 4; ++ks)                                                 \
          dst[ks] = *(const f16x8*)(bs + ((C) * 8 + ks * 2 + (T)) * 512 + lane * 8); }

// A fragments (16 K or Q rows per wave) fp32 -> f16 into dst[4]
#define LOADA(dst, src)                                                              \
    { const float* rp = (src) + (tok0 + wv * 16 + m) * DIM;                          \
      _Pragma("unroll")                                                              \
      for (int ks = 0; ks < 4; ++ks) {                                               \
          int d0 = ks * 32 + quad * 8;                                               \
          float4 x = *(const float4*)(rp + d0);                                      \
          float4 y = *(const float4*)(rp + d0 + 4);                                  \
          dst[ks] = (f16x8){(_Float16)x.x, (_Float16)x.y, (_Float16)x.z, (_Float16)x.w, \
                            (_Float16)y.x, (_Float16)y.y, (_Float16)y.z, (_Float16)y.w}; } }

// Fused step: k_proj and q_proj on the same B tile; est += sign(k)*q directly.
// Near-zero k_proj -> per-wave candidate queue (LDS atomics, no cross-wave traffic).
// encode: tl_local(4b) | p(8b)<<4 | sign_applied<<12
#define F_STEP(C, T, buf)                                                            \
    { f32x4 k0 = {0,0,0,0}, q0 = {0,0,0,0};                                          \
      _Pragma("unroll")                                                              \
      for (int ks = 0; ks < 4; ++ks) {                                               \
          k0 = __builtin_amdgcn_mfma_f32_16x16x32_f16(ak[ks], buf[ks], k0, 0,0,0);   \
          q0 = __builtin_amdgcn_mfma_f32_16x16x32_f16(aq[ks], buf[ks], q0, 0,0,0);   \
      }                                                                              \
      _Pragma("unroll")                                                              \
      for (int r = 0; r < 4; ++r) {                                                  \
          uint32_t s0 = __float_as_uint(k0[r]) & 0x80000000u;                        \
          est[r] += __uint_as_float(__float_as_uint(q0[r]) ^ s0);                    \
          if (__builtin_expect(fabsf(k0[r]) < TAU, 0)) {                             \
              int idx = atomicAdd(&qn[wv], 1);                                       \
              if (idx < QCAPW) {                                                     \
                  qmeta[wv][idx] = (uint32_t)(quad * 4 + r)                          \
                      | ((uint32_t)((C) * 32 + (T) * 16 + m) << 4)                   \
                      | ((s0 ? 0u : 1u) << 12);                                      \
                  qval[wv][idx] = q0[r];                                             \
              }                                                                      \
          } } }

// Persistent-block design: rounds 5-8 showed (a) residency pinned ~8 waves/CU
// regardless of LDS/VGPR/block shape, (b) duration insensitive to L3-warm
// replay (not memory-bound), (c) per-block latency constant ~17-19us -> the
// per-block serial walls (stage + vmcnt-drain barriers + refine tail) ARE the
// bottleneck. So: 512 blocks (2/CU), stage 64KB B once, ONE barrier, then a
// barrier-free grid-stride loop over 8 token-tiles per block. Refine is
// wave-cooperative (64-lane fp64 dot + shfl reduce + global atomic patch).
// Register-resident B (rounds 1/3/4) always spilled: keep B in LDS.
__global__ __launch_bounds__(256, 2) void qjl_main(
    const float* __restrict__ qg, const float* __restrict__ kg,
    const float* __restrict__ Sg, const _Float16* __restrict__ ws,
    float* __restrict__ out, int ntiles)
{
    __shared__ _Float16 bs[32768];          // 64 KB: all 64 B-fragments
    __shared__ uint32_t qmeta[4][QCAPW];
    __shared__ float    qval[4][QCAPW];
    __shared__ int      qn[4];

    const int tid = threadIdx.x, lane = tid & 63, wv = tid >> 6;
    const int m = lane & 15, quad = lane >> 4;

    // ---- stage all of B once (L2-resident ws -> LDS, async, coalesced) ----
    {
        const char* gsrc = (const char*)ws + tid * 16;
        char* ldst = (char*)bs + tid * 16;
        #pragma unroll
        for (int r = 0; r < 16; ++r)
            __builtin_amdgcn_global_load_lds(
                (const __attribute__((address_space(1))) void*)(gsrc + r * 4096),
                (__attribute__((address_space(3))) void*)(ldst + r * 4096),
                16, 0, 0);
    }
    __syncthreads();   // the ONLY block-wide barrier

    f16x8 ak[4], aq[4];        // A fragments: 16 K rows + 16 Q rows
    f16x8 tA[4], tB[4];        // B tile double buffer (fed from LDS)

    for (int tile = blockIdx.x; tile < ntiles; tile += NBLK) {
        const long tok0 = (long)tile * 64;
        if (lane == 0) qn[wv] = 0;

        LOADA(ak, kg);
        LOADA(aq, qg);
        float est[4] = {0.f, 0.f, 0.f, 0.f};

        LOADT(tA, 0, 0);
        LOADT(tB, 0, 1);
        F_STEP(0, 0, tA); LOADT(tA, 1, 0);
        F_STEP(0, 1, tB); LOADT(tB, 1, 1);
        F_STEP(1, 0, tA); LOADT(tA, 2, 0);
        F_STEP(1, 1, tB); LOADT(tB, 2, 1);
        F_STEP(2, 0, tA); LOADT(tA, 3, 0);
        F_STEP(2, 1, tB); LOADT(tB, 3, 1);
        F_STEP(3, 0, tA); LOADT(tA, 4, 0);
        F_STEP(3, 1, tB); LOADT(tB, 4, 1);
        F_STEP(4, 0, tA); LOADT(tA, 5, 0);
        F_STEP(4, 1, tB); LOADT(tB, 5, 1);
        F_STEP(5, 0, tA); LOADT(tA, 6, 0);
        F_STEP(5, 1, tB); LOADT(tB, 6, 1);
        F_STEP(6, 0, tA); LOADT(tA, 7, 0);
        F_STEP(6, 1, tB); LOADT(tB, 7, 1);
        F_STEP(7, 0, tA);
        F_STEP(7, 1, tB);

        // ---- reduce est over the 16 proj-lanes; float4 store per m==0 lane ----
        #pragma unroll
        for (int r = 0; r < 4; ++r) {
            float e = est[r];
            e += __shfl_xor(e, 1);
            e += __shfl_xor(e, 2);
            e += __shfl_xor(e, 4);
            e += __shfl_xor(e, 8);
            est[r] = DEQ * e;
        }
        if (m == 0) {
            float4 o = {est[0], est[1], est[2], est[3]};
            *(float4*)(out + tok0 + wv * 16 + quad * 4) = o;
        }
        // est stores must land before the atomic patches below (same addresses)
        asm volatile("s_waitcnt vmcnt(0) lgkmcnt(0)" ::: "memory");

        // ---- refine: wave-cooperative exact fp64 k-dot per candidate ----
        int nc = qn[wv] < QCAPW ? qn[wv] : QCAPW;
        for (int i = 0; i < nc; ++i) {
            uint32_t mm = qmeta[wv][i];
            int tl = mm & 15;
            int p  = (mm >> 4) & 255;
            int sf = (mm >> 12) & 1;
            const float2* kr = (const float2*)(kg + (tok0 + wv * 16 + tl) * DIM);
            const float2* sr = (const float2*)(Sg + (long)p * DIM);
            float2 kv = kr[lane], sv = sr[lane];
            double d = (double)kv.x * (double)sv.x + (double)kv.y * (double)sv.y;
            #pragma unroll
            for (int off = 1; off < 64; off <<= 1)
                d += __shfl_xor(d, off);
            int st = (d > 0.0) ? 1 : 0;
            if (st != sf && lane == 0) {
                float sg = sf ? 1.f : -1.f;
                atomicAdd(&out[tok0 + wv * 16 + tl], -2.f * DEQ * qval[wv][i] * sg);
            }
        }
    }
}

extern "C" void kernel_launch(void* const* d_in, const int* in_sizes, int n_in,
                              void* d_out, int out_size, void* d_ws, size_t ws_size,
                              hipStream_t stream) {
    const float* q = (const float*)d_in[0];
    const float* k = (const float*)d_in[1];
    const float* S = (const float*)d_in[2];
    float* out = (float*)d_out;
    _Float16* ws = (_Float16*)d_ws;
    hipLaunchKernelGGL(qjl_prep, dim3(16), dim3(256), 0, stream, S, ws);
    int ntiles = out_size / 64;     // 262144 / 64 = 4096 tiles; 8 per block
    hipLaunchKernelGGL(qjl_main, dim3(NBLK), dim3(256), 0, stream, q, k, S, ws, out, ntiles);
}